// Round 1
// baseline (3634.239 us; speedup 1.0000x reference)
//
#include <hip/hip_runtime.h>

#define T_SEQ 2048
#define HDIM  128
#define GDIM  512
#define BATCH 256

typedef _Float16 f16;
typedef _Float16 f16x2 __attribute__((ext_vector_type(2)));
typedef _Float16 f16x8 __attribute__((ext_vector_type(8)));

#if __has_builtin(__builtin_amdgcn_fdot2)
__device__ __forceinline__ float dot2(f16x2 a, f16x2 b, float c) {
    return __builtin_amdgcn_fdot2(a, b, c, false);
}
#else
__device__ __forceinline__ float dot2(f16x2 a, f16x2 b, float c) {
    return c + (float)a[0] * (float)b[0] + (float)a[1] * (float)b[1];
}
#endif

__device__ __forceinline__ f16x2 mk2(float a, float b) {
    f16x2 r; r[0] = (f16)a; r[1] = (f16)b; return r;
}
// extract half2 pair m (0..3) from an 8-wide f16 vector (free after inlining:
// f16x8 = 4 VGPRs, each VGPR is exactly one f16x2)
__device__ __forceinline__ f16x2 pr(f16x8 v, int m) {
    f16x2 r; r[0] = v[2 * m]; r[1] = v[2 * m + 1]; return r;
}

__device__ __forceinline__ float sigm(float x) {
    return __builtin_amdgcn_rcpf(1.0f + __expf(-x));
}
// tanh(x) = 1 - 2/(e^{2x}+1); exp overflow -> rcp(inf)=0 -> +/-1 saturation is exact
__device__ __forceinline__ float tanh_fast(float x) {
    float e = __expf(2.0f * x);
    return 1.0f - 2.0f * __builtin_amdgcn_rcpf(e + 1.0f);
}

// One block per batch element. 512 threads: thread t owns gate-row t of
// W_hh_l0 (regs, f16), gate-row t of W_ih_l1 (regs, f16), gate-row t of
// W_hh_l1 (k<64 in regs, k>=64 in LDS). Layers are software-pipelined:
// iteration i computes layer0 step i and layer1 step i-1 concurrently
// (both consume the same LDS-resident h0 state).
//
// launch_bounds(512, 1): grid == CU count -> only one block is ever resident
// per CU; asking for 2 just caps VGPRs at 128 and starves the scheduler.
//
// Compute phase uses 4 partial accumulators per gate row (a0: 4x16-link
// chains, a1: 4x32-link chains) -> 8 independent dot2 chains per thread so
// 2 waves/SIMD can cover the dot2 forwarding latency (was: 2 serial chains
// of 64/128 links -> latency-bound at VALUBusy 56%).
__global__ __launch_bounds__(512, 1)
void lstm_fused(const float* __restrict__ x,
                const float* __restrict__ Wih0,
                const float* __restrict__ Whh0,
                const float* __restrict__ bih0,
                const float* __restrict__ bhh0,
                const float* __restrict__ Wih1,
                const float* __restrict__ Whh1,
                const float* __restrict__ bih1,
                const float* __restrict__ bhh1,
                const float* __restrict__ Wfc,
                const float* __restrict__ bfc,
                float* __restrict__ out)
{
    // W_hh_l1 high-k half: 512 rows x 64 halves, padded to 72 halves/row
    // (144 B = 9*16 B) so lane-t b128 reads stripe all 32 banks. 72 KB.
    __shared__ __align__(16) f16   wh1s[GDIM * 72];
    __shared__ __align__(16) float xs[T_SEQ];       // whole x[b,:] (8 KB)
    __shared__ __align__(16) f16   h0h[HDIM];       // h0 state, f16 (dot input)
    __shared__ __align__(16) f16   h1h[HDIM];       // h1 state, f16
    __shared__ float h0f[HDIM], h1f[HDIM];          // fp32 copies for outputs
    __shared__ float g0[GDIM], g1[GDIM];            // gate preactivations

    const int t = threadIdx.x;
    const int b = blockIdx.x;

    // stage the full input sequence for this batch element (coalesced)
    ((float4*)xs)[t] = ((const float4*)(x + (size_t)b * T_SEQ))[t];

    // ---- load per-thread weights into registers (f16-packed) ----
    f16x2 w0[64];  // W_hh_l0[t, 0:128]
    f16x2 wi[64];  // W_ih_l1[t, 0:128]
    f16x2 wl[32];  // W_hh_l1[t, 0:64]
    {
        const float4* p0 = (const float4*)(Whh0 + t * HDIM);
        const float4* p1 = (const float4*)(Wih1 + t * HDIM);
        const float4* p2 = (const float4*)(Whh1 + t * HDIM);
#pragma unroll
        for (int c = 0; c < 32; ++c) {
            float4 v = p0[c];
            w0[2 * c]     = mk2(v.x, v.y);
            w0[2 * c + 1] = mk2(v.z, v.w);
        }
#pragma unroll
        for (int c = 0; c < 32; ++c) {
            float4 v = p1[c];
            wi[2 * c]     = mk2(v.x, v.y);
            wi[2 * c + 1] = mk2(v.z, v.w);
        }
#pragma unroll
        for (int c = 0; c < 16; ++c) {
            float4 v = p2[c];
            wl[2 * c]     = mk2(v.x, v.y);
            wl[2 * c + 1] = mk2(v.z, v.w);
        }
        // W_hh_l1[t, 64:128] -> LDS (padded rows)
        f16x2* dst = (f16x2*)(wh1s + t * 72);
#pragma unroll
        for (int c = 0; c < 16; ++c) {
            float4 v = p2[16 + c];
            dst[2 * c]     = mk2(v.x, v.y);
            dst[2 * c + 1] = mk2(v.z, v.w);
        }
    }
    const float wx0   = Wih0[t];            // W_ih_l0 is [512,1]
    const float bias0 = bih0[t] + bhh0[t];
    const float bias1 = bih1[t] + bhh1[t];

    if (t < HDIM) {
        h0h[t] = (f16)0.f; h1h[t] = (f16)0.f;
        h0f[t] = 0.f;      h1f[t] = 0.f;
    }
    float c0r = 0.f, c1r = 0.f;  // cell state lives in its update thread
    __syncthreads();

    const f16x8* h0p  = (const f16x8*)h0h;
    const f16x8* h1p  = (const f16x8*)h1h;
    const f16x8* wrow = (const f16x8*)(wh1s + t * 72);

    for (int i = 0; i <= T_SEQ; ++i) {
        // ---- compute phase: all 512 threads, 192 dot2 each ----
        // 8 independent partial-accumulator chains (reassociated f32 sums).
        float s0a = (i < T_SEQ ? xs[i] : 0.f) * wx0 + bias0;
        float s0b = 0.f, s0c = 0.f, s0d = 0.f;
        float s1a = bias1;
        float s1b = 0.f, s1c = 0.f, s1d = 0.f;
#pragma unroll
        for (int c = 0; c < 16; ++c) {          // k = 0..127 of h0 (broadcast)
            f16x8 h = h0p[c];
            s0a = dot2(w0[4 * c + 0], pr(h, 0), s0a);   // layer0 recurrence
            s0b = dot2(w0[4 * c + 1], pr(h, 1), s0b);
            s0c = dot2(w0[4 * c + 2], pr(h, 2), s0c);
            s0d = dot2(w0[4 * c + 3], pr(h, 3), s0d);
            s1a = dot2(wi[4 * c + 0], pr(h, 0), s1a);   // layer1 input matvec
            s1b = dot2(wi[4 * c + 1], pr(h, 1), s1b);
            s1c = dot2(wi[4 * c + 2], pr(h, 2), s1c);
            s1d = dot2(wi[4 * c + 3], pr(h, 3), s1d);
        }
#pragma unroll
        for (int c = 0; c < 8; ++c) {           // k = 0..63 of h1, reg weights
            f16x8 h = h1p[c];
            s1a = dot2(wl[4 * c + 0], pr(h, 0), s1a);
            s1b = dot2(wl[4 * c + 1], pr(h, 1), s1b);
            s1c = dot2(wl[4 * c + 2], pr(h, 2), s1c);
            s1d = dot2(wl[4 * c + 3], pr(h, 3), s1d);
        }
#pragma unroll
        for (int c = 0; c < 8; ++c) {           // k = 64..127 of h1, LDS weights
            f16x8 h = h1p[8 + c];
            f16x8 w = wrow[c];
            s1a = dot2(pr(w, 0), pr(h, 0), s1a);
            s1b = dot2(pr(w, 1), pr(h, 1), s1b);
            s1c = dot2(pr(w, 2), pr(h, 2), s1c);
            s1d = dot2(pr(w, 3), pr(h, 3), s1d);
        }
        g0[t] = (s0a + s0b) + (s0c + s0d);
        g1[t] = (s1a + s1b) + (s1c + s1d);
        __syncthreads();

        // ---- update phase: waves 0-1 -> layer0 unit t, waves 2-3 -> layer1 ----
        if (t < 128) {
            if (i < T_SEQ) {
                float gi = sigm(g0[t]);
                float gf = sigm(g0[t + 128]);
                float gg = tanh_fast(g0[t + 256]);
                float go = sigm(g0[t + 384]);
                c0r = gf * c0r + gi * gg;
                float h = go * tanh_fast(c0r);
                h0h[t] = (f16)h;
                h0f[t] = h;
            }
        } else if (t < 256) {
            if (i >= 1) {
                int j = t - 128;
                float gi = sigm(g1[j]);
                float gf = sigm(g1[j + 128]);
                float gg = tanh_fast(g1[j + 256]);
                float go = sigm(g1[j + 384]);
                c1r = gf * c1r + gi * gg;
                float h = go * tanh_fast(c1r);
                h1h[j] = (f16)h;
                h1f[j] = h;
            }
        }
        __syncthreads();
    }

    // ---- outputs: out = [ y(256) | h_n(2*256*128) | c_n(2*256*128) ] ----
    float* hn = out + BATCH;
    float* cn = out + BATCH + 2 * BATCH * HDIM;
    if (t < 128) {
        hn[(size_t)b * HDIM + t] = h0f[t];
        cn[(size_t)b * HDIM + t] = c0r;
    } else if (t < 256) {
        int j = t - 128;
        hn[BATCH * HDIM + (size_t)b * HDIM + j] = h1f[j];
        cn[BATCH * HDIM + (size_t)b * HDIM + j] = c1r;
    }
    // y[b] = h1_final . W_fc + b_fc  (wave 0 reduction)
    if (t < 64) {
        float p = h1f[t] * Wfc[t] + h1f[t + 64] * Wfc[t + 64];
#pragma unroll
        for (int o = 32; o >= 1; o >>= 1) p += __shfl_down(p, o);
        if (t == 0) out[b] = p + bfc[0];
    }
}

extern "C" void kernel_launch(void* const* d_in, const int* in_sizes, int n_in,
                              void* d_out, int out_size, void* d_ws, size_t ws_size,
                              hipStream_t stream) {
    const float* x    = (const float*)d_in[0];
    const float* Wih0 = (const float*)d_in[1];
    const float* Whh0 = (const float*)d_in[2];
    const float* bih0 = (const float*)d_in[3];
    const float* bhh0 = (const float*)d_in[4];
    const float* Wih1 = (const float*)d_in[5];
    const float* Whh1 = (const float*)d_in[6];
    const float* bih1 = (const float*)d_in[7];
    const float* bhh1 = (const float*)d_in[8];
    const float* Wfc  = (const float*)d_in[9];
    const float* bfc  = (const float*)d_in[10];
    lstm_fused<<<BATCH, 512, 0, stream>>>(x, Wih0, Whh0, bih0, bhh0,
                                          Wih1, Whh1, bih1, bhh1,
                                          Wfc, bfc, (float*)d_out);
}

// Round 2
// 3079.463 us; speedup vs baseline: 1.1802x; 1.1802x over previous
//
#include <hip/hip_runtime.h>

#define T_SEQ 2048
#define HDIM  128
#define GDIM  512
#define BATCH 256

typedef _Float16 f16;
typedef _Float16 f16x2 __attribute__((ext_vector_type(2)));
typedef _Float16 f16x8 __attribute__((ext_vector_type(8)));

#if __has_builtin(__builtin_amdgcn_fdot2)
__device__ __forceinline__ float dot2(f16x2 a, f16x2 b, float c) {
    return __builtin_amdgcn_fdot2(a, b, c, false);
}
#else
__device__ __forceinline__ float dot2(f16x2 a, f16x2 b, float c) {
    return c + (float)a[0] * (float)b[0] + (float)a[1] * (float)b[1];
}
#endif

__device__ __forceinline__ f16x2 mk2(float a, float b) {
    f16x2 r; r[0] = (f16)a; r[1] = (f16)b; return r;
}
// extract half2 pair m (0..3) from an 8-wide f16 vector (free after inlining:
// f16x8 = 4 VGPRs, each VGPR is exactly one f16x2)
__device__ __forceinline__ f16x2 pr(f16x8 v, int m) {
    f16x2 r; r[0] = v[2 * m]; r[1] = v[2 * m + 1]; return r;
}

__device__ __forceinline__ float sigm(float x) {
    return __builtin_amdgcn_rcpf(1.0f + __expf(-x));
}
// tanh(x) = 1 - 2/(e^{2x}+1); exp overflow -> rcp(inf)=0 -> +/-1 saturation is exact
__device__ __forceinline__ float tanh_fast(float x) {
    float e = __expf(2.0f * x);
    return 1.0f - 2.0f * __builtin_amdgcn_rcpf(e + 1.0f);
}

// One block per batch element, 1024 threads (16 waves/CU).
//
// The three 512x128 f16 matvecs per timestep (layer0 recurrence, layer1
// input matvec, layer1 recurrence) are split so EVERY thread owns exactly
// 96 weight halves in registers (96 VGPRs):
//   group A (t < 512, r = t):  wa = W_hh_l0[r, 0:128], wb = W_hh_l1[r, 0:64]
//   group B (t >= 512, r = t-512): wa = W_ih_l1[r, 0:128], wb = W_hh_l1[r, 64:128]
// Both groups index the SAME register arrays (conditionally loaded) so the
// allocator sees 96 weight regs, not 192. g1[r] = g1a[r] (A's partial) +
// g1b[r] (B's partial), summed in the update phase.
//
// Rationale (round-1 post-mortem): the 512-thread version kept 160 weight
// VGPRs per thread against a 128-reg budget -> permanent scratch spills
// (WRITE_SIZE 41 MB vs 0.5 MB true output). 96 regs fits; spills vanish,
// per-thread dot2 count halves (192 -> 96), and 4 waves/SIMD (vs 2) cover
// the dot2 forwarding latency.
//
// Layers stay software-pipelined: iteration i computes layer0 step i and
// layer1 step i-1 concurrently from the same LDS-resident h-state.
__global__ __launch_bounds__(1024)
void lstm_fused(const float* __restrict__ x,
                const float* __restrict__ Wih0,
                const float* __restrict__ Whh0,
                const float* __restrict__ bih0,
                const float* __restrict__ bhh0,
                const float* __restrict__ Wih1,
                const float* __restrict__ Whh1,
                const float* __restrict__ bih1,
                const float* __restrict__ bhh1,
                const float* __restrict__ Wfc,
                const float* __restrict__ bfc,
                float* __restrict__ out)
{
    __shared__ __align__(16) float xs[T_SEQ];       // whole x[b,:] (8 KB)
    __shared__ __align__(16) f16   h0h[HDIM];       // h0 state, f16 (dot input)
    __shared__ __align__(16) f16   h1h[HDIM];       // h1 state, f16
    __shared__ float h0f[HDIM], h1f[HDIM];          // fp32 copies for outputs
    __shared__ float g0[GDIM];                      // layer0 gate preactivations
    __shared__ float g1a[GDIM], g1b[GDIM];          // layer1 partials (A + B)

    const int t  = threadIdx.x;
    const int b  = blockIdx.x;
    const bool gA = (t < 512);
    const int r  = t & 511;

    // stage the full input sequence for this batch element (coalesced)
    if (gA)
        ((float4*)xs)[t] = ((const float4*)(x + (size_t)b * T_SEQ))[t];

    // ---- load per-thread weights into registers (f16-packed, 96 VGPRs) ----
    f16x2 wa[64];  // A: W_hh_l0[r, 0:128] | B: W_ih_l1[r, 0:128]
    f16x2 wb[32];  // A: W_hh_l1[r, 0:64]  | B: W_hh_l1[r, 64:128]
    {
        const float4* pa = (const float4*)((gA ? Whh0 : Wih1) + r * HDIM);
        const float4* pb = (const float4*)(Whh1 + r * HDIM + (gA ? 0 : 64));
#pragma unroll
        for (int c = 0; c < 32; ++c) {
            float4 v = pa[c];
            wa[2 * c]     = mk2(v.x, v.y);
            wa[2 * c + 1] = mk2(v.z, v.w);
        }
#pragma unroll
        for (int c = 0; c < 16; ++c) {
            float4 v = pb[c];
            wb[2 * c]     = mk2(v.x, v.y);
            wb[2 * c + 1] = mk2(v.z, v.w);
        }
    }
    // A: x-weight + layer0 bias | B: no x-term (xw=0), layer1 bias
    const float xw   = gA ? Wih0[r] : 0.f;
    const float bias = gA ? (bih0[r] + bhh0[r]) : (bih1[r] + bhh1[r]);

    if (t < HDIM) {
        h0h[t] = (f16)0.f; h1h[t] = (f16)0.f;
        h0f[t] = 0.f;      h1f[t] = 0.f;
    }
    float c0r = 0.f, c1r = 0.f;  // cell state lives in its update thread
    __syncthreads();

    const f16x8* h0p  = (const f16x8*)h0h;
    // A consumes h1[0:64] (pairs wb = Whh1[:,0:64]); B consumes h1[64:128]
    const f16x8* hsel = ((const f16x8*)h1h) + (gA ? 0 : 8);

    for (int i = 0; i <= T_SEQ; ++i) {
        // ---- compute phase: all 1024 threads, 96 dot2 each, 4 chains ----
        float sa = (i < T_SEQ ? xs[i] : 0.f) * xw + bias;
        float sb = 0.f, sc = 0.f, sd = 0.f;
#pragma unroll
        for (int c = 0; c < 16; ++c) {          // k = 0..127 of h0 (broadcast)
            f16x8 h = h0p[c];
            sa = dot2(wa[4 * c + 0], pr(h, 0), sa);
            sb = dot2(wa[4 * c + 1], pr(h, 1), sb);
            sa = dot2(wa[4 * c + 2], pr(h, 2), sa);
            sb = dot2(wa[4 * c + 3], pr(h, 3), sb);
        }
#pragma unroll
        for (int c = 0; c < 8; ++c) {           // 64 halves of h1 (A: low, B: high)
            f16x8 h = hsel[c];
            sc = dot2(wb[4 * c + 0], pr(h, 0), sc);
            sd = dot2(wb[4 * c + 1], pr(h, 1), sd);
            sc = dot2(wb[4 * c + 2], pr(h, 2), sc);
            sd = dot2(wb[4 * c + 3], pr(h, 3), sd);
        }
        if (gA) {
            g0[r]  = sa + sb;          // full layer0 preactivation
            g1a[r] = sc + sd;          // layer1 recurrence, k = 0..63
        } else {
            g1b[r] = (sa + sb) + (sc + sd);  // layer1 input matvec + k = 64..127
        }
        __syncthreads();

        // ---- update phase: waves 0-1 -> layer0, waves 8-9 -> layer1 ----
        if (t < 128) {
            if (i < T_SEQ) {
                float gi = sigm(g0[t]);
                float gf = sigm(g0[t + 128]);
                float gg = tanh_fast(g0[t + 256]);
                float go = sigm(g0[t + 384]);
                c0r = gf * c0r + gi * gg;
                float h = go * tanh_fast(c0r);
                h0h[t] = (f16)h;
                h0f[t] = h;
            }
        } else if (t >= 512 && t < 640) {
            if (i >= 1) {
                int j = t - 512;
                float gi = sigm(g1a[j]       + g1b[j]);
                float gf = sigm(g1a[j + 128] + g1b[j + 128]);
                float gg = tanh_fast(g1a[j + 256] + g1b[j + 256]);
                float go = sigm(g1a[j + 384] + g1b[j + 384]);
                c1r = gf * c1r + gi * gg;
                float h = go * tanh_fast(c1r);
                h1h[j] = (f16)h;
                h1f[j] = h;
            }
        }
        __syncthreads();
    }

    // ---- outputs: out = [ y(256) | h_n(2*256*128) | c_n(2*256*128) ] ----
    float* hn = out + BATCH;
    float* cn = out + BATCH + 2 * BATCH * HDIM;
    if (t < 128) {
        hn[(size_t)b * HDIM + t] = h0f[t];
        cn[(size_t)b * HDIM + t] = c0r;
    } else if (t >= 512 && t < 640) {
        int j = t - 512;
        hn[BATCH * HDIM + (size_t)b * HDIM + j] = h1f[j];
        cn[BATCH * HDIM + (size_t)b * HDIM + j] = c1r;
    }
    // y[b] = h1_final . W_fc + b_fc  (wave 0 reduction)
    if (t < 64) {
        float p = h1f[t] * Wfc[t] + h1f[t + 64] * Wfc[t + 64];
#pragma unroll
        for (int o = 32; o >= 1; o >>= 1) p += __shfl_down(p, o);
        if (t == 0) out[b] = p + bfc[0];
    }
}

extern "C" void kernel_launch(void* const* d_in, const int* in_sizes, int n_in,
                              void* d_out, int out_size, void* d_ws, size_t ws_size,
                              hipStream_t stream) {
    const float* x    = (const float*)d_in[0];
    const float* Wih0 = (const float*)d_in[1];
    const float* Whh0 = (const float*)d_in[2];
    const float* bih0 = (const float*)d_in[3];
    const float* bhh0 = (const float*)d_in[4];
    const float* Wih1 = (const float*)d_in[5];
    const float* Whh1 = (const float*)d_in[6];
    const float* bih1 = (const float*)d_in[7];
    const float* bhh1 = (const float*)d_in[8];
    const float* Wfc  = (const float*)d_in[9];
    const float* bfc  = (const float*)d_in[10];
    lstm_fused<<<BATCH, 1024, 0, stream>>>(x, Wih0, Whh0, bih0, bhh0,
                                           Wih1, Whh1, bih1, bhh1,
                                           Wfc, bfc, (float*)d_out);
}